// Round 9
// baseline (274.215 us; speedup 1.0000x reference)
//
#include <hip/hip_runtime.h>
#include <math.h>

#define Bb   4
#define Tt   2048
#define DIN  1024
#define DOUT 1024
#define NH   16
#define HD   64
#define BT   (Bb * Tt)   // 8192 tokens

typedef __attribute__((ext_vector_type(8))) short bf16x8;
typedef __attribute__((ext_vector_type(4))) float f32x4;
typedef __attribute__((ext_vector_type(4))) short short4v;

__device__ __forceinline__ short f2bf(float f) {
  union { float f; unsigned u; } v; v.f = f;
  unsigned r = v.u + 0x7FFFu + ((v.u >> 16) & 1u);
  return (short)(r >> 16);
}

// packed f32x2 -> bf16x2 (RNE), single HW op on gfx950
__device__ __forceinline__ unsigned pkbf(float a, float b) {
  unsigned r;
  asm("v_cvt_pk_bf16_f32 %0, %1, %2" : "=v"(r) : "v"(a), "v"(b));
  return r;
}

#define MFMA16(a, b, c) __builtin_amdgcn_mfma_f32_16x16x32_bf16((a), (b), (c), 0, 0, 0)

// async global->LDS, 16B per lane; LDS dest = wave-uniform base + lane*16
__device__ __forceinline__ void gload16(const short* g, short* l) {
  __builtin_amdgcn_global_load_lds(
      (const __attribute__((address_space(1))) void*)g,
      (__attribute__((address_space(3))) void*)l, 16, 0, 0);
}

// ---------------------------------------------------------------------------
// cvt_x: fp32 -> bf16
// ---------------------------------------------------------------------------
__global__ __launch_bounds__(256) void cvt_x(const float* __restrict__ x,
                                             short* __restrict__ xb) {
  const int i = (blockIdx.x * 256 + threadIdx.x) * 4;
  float4 v = *(const float4*)(x + i);
  uint2 o;
  o.x = pkbf(v.x, v.y);
  o.y = pkbf(v.z, v.w);
  *(uint2*)(xb + i) = o;
}

// ---------------------------------------------------------------------------
// cvt_wt: W [K][N] fp32 -> Wt [N][K] bf16 (transpose+convert), 64x64 tiles.
// ---------------------------------------------------------------------------
__global__ __launch_bounds__(256) void cvt_wt(
    const float* __restrict__ W0, const float* __restrict__ W1,
    const float* __restrict__ W2, const float* __restrict__ W3,
    short* __restrict__ O0, short* __restrict__ O1,
    short* __restrict__ O2, short* __restrict__ O3) {
  const float* W = blockIdx.z == 0 ? W0 : blockIdx.z == 1 ? W1
                 : blockIdx.z == 2 ? W2 : W3;
  short* O = blockIdx.z == 0 ? O0 : blockIdx.z == 1 ? O1
           : blockIdx.z == 2 ? O2 : O3;
  __shared__ short t[64][65];
  const int n0 = blockIdx.x * 64, k0 = blockIdx.y * 64;
  const int tid = threadIdx.x;
#pragma unroll
  for (int i = 0; i < 16; ++i) {
    const int e = tid + 256 * i;
    const int k = e >> 6, n = e & 63;
    t[n][k] = f2bf(W[(size_t)(k0 + k) * DOUT + n0 + n]);
  }
  __syncthreads();
#pragma unroll
  for (int i = 0; i < 16; ++i) {
    const int e = tid + 256 * i;
    const int n = e >> 6, k = e & 63;
    O[(size_t)(n0 + n) * DIN + k0 + k] = t[n][k];
  }
}

// ---------------------------------------------------------------------------
// bf16 MFMA GEMM: C[M,N] = A[M,K] @ Bt^T  (Bt[N][K]).  (unchanged from R6)
// ---------------------------------------------------------------------------
template <bool QKV, bool F32OUT, bool BIAS>
__global__ __launch_bounds__(256) void gemm_bf16(
    const short* __restrict__ A, const short* __restrict__ Bt0,
    const float* __restrict__ bias, void* __restrict__ Cout,
    int M, int N, int K, float qsc) {
  constexpr int BM = 128, BN = 128, BK = 64;
  __shared__ __align__(16) short Asm[BM][BK];
  __shared__ __align__(16) short Bsm[BN][BK];

  const short* Bt = Bt0;
  short* Cb16 = (short*)Cout;
  float oscale = 1.0f;
  if (QKV) {
    const int z = blockIdx.z;
    Bt += (size_t)z * N * K;
    Cb16 += (size_t)z * M * N;
    if (z == 0) oscale = qsc;
  }

  const int tid = threadIdx.x;
  const int wid = tid >> 6, lane = tid & 63;
  const int lhi = lane >> 4, llo = lane & 15;
  const int bm = blockIdx.x * BM, bn = blockIdx.y * BN;
  const int wr = (wid >> 1) * 64, wc = (wid & 1) * 64;

  const int srow = lane >> 3;
  const int sca = ((lane & 7) ^ srow) * 8;

  f32x4 acc[4][4];
#pragma unroll
  for (int i = 0; i < 4; ++i)
#pragma unroll
    for (int j = 0; j < 4; ++j)
#pragma unroll
      for (int r = 0; r < 4; ++r) acc[i][j][r] = 0.0f;

  for (int k0 = 0; k0 < K; k0 += BK) {
    __syncthreads();
#pragma unroll
    for (int iss = 0; iss < 4; ++iss) {
      const int ra = wid * 32 + iss * 8 + srow;
      gload16(A + (size_t)(bm + ra) * K + k0 + sca, &Asm[wid * 32 + iss * 8][0]);
      gload16(Bt + (size_t)(bn + ra) * K + k0 + sca, &Bsm[wid * 32 + iss * 8][0]);
    }
    __syncthreads();

#pragma unroll
    for (int ks = 0; ks < 2; ++ks) {
      bf16x8 af[4], bfr[4];
#pragma unroll
      for (int i = 0; i < 4; ++i) {
        const int row = wr + i * 16 + llo;
        af[i] = *(const bf16x8*)&Asm[row][((ks * 4 + lhi) ^ (row & 7)) * 8];
      }
#pragma unroll
      for (int j = 0; j < 4; ++j) {
        const int row = wc + j * 16 + llo;
        bfr[j] = *(const bf16x8*)&Bsm[row][((ks * 4 + lhi) ^ (row & 7)) * 8];
      }
      __builtin_amdgcn_s_setprio(1);
#pragma unroll
      for (int i = 0; i < 4; ++i)
#pragma unroll
        for (int j = 0; j < 4; ++j)
          acc[i][j] = MFMA16(af[i], bfr[j], acc[i][j]);
      __builtin_amdgcn_s_setprio(0);
    }
  }

#pragma unroll
  for (int i = 0; i < 4; ++i)
#pragma unroll
    for (int j = 0; j < 4; ++j)
#pragma unroll
      for (int r = 0; r < 4; ++r) {
        const int row = bm + wr + i * 16 + lhi * 4 + r;
        const int col = bn + wc + j * 16 + llo;
        float v = acc[i][j][r] * oscale;
        if (BIAS) v += bias[col];
        if (F32OUT)
          ((float*)Cout)[(size_t)row * N + col] = v;
        else
          Cb16[(size_t)row * N + col] = f2bf(v);
      }
}

// ---------------------------------------------------------------------------
// Causal flash attention V2: swapped QK^T + permuted-K LDS so the PV
// B-operand is fully in-lane (no P LDS round-trip, no cross-lane shuffles).
// K and V staged via global_load_lds w16 (inverse-swizzled source, linear
// dest, XOR col-swizzle chunk^(row&7) on reads). 8 waves x 32 q-rows.
// Q pre-scaled by 0.125*log2e in the Q-GEMM -> exp2 directly.
// ---------------------------------------------------------------------------
__global__ __launch_bounds__(512, 2) void attn_bf16(
    const short* __restrict__ Q, const short* __restrict__ K,
    const short* __restrict__ Vt_g, short* __restrict__ Ctx) {
  __shared__ __align__(16) short Ks[2][64][64];  // rows permuted by pi(m)
  __shared__ __align__(16) short Vt[2][64][64];  // [d][kv], cols swizzled

  const int bid = blockIdx.x;
  const int qt = 7 - (bid >> 6);   // longest-first
  const int bh = bid & 63;
  const int b = bh >> 4, h = bh & 15;
  const int tid = threadIdx.x;
  const int wid = tid >> 6, lane = tid & 63;
  const int lhi = lane >> 4, llo = lane & 15;
  const int lm7 = llo & 7;

  const size_t base_bt = (size_t)b * Tt;
  const int headoff = h * HD;
  const int q0 = qt * 256 + wid * 32;

  // Q fragments (B-operand): qf[rb][kh][e] = Q[q0+rb*16+llo][kh*32+lhi*8+e]
  bf16x8 qf[2][2];
#pragma unroll
  for (int rb = 0; rb < 2; ++rb)
#pragma unroll
    for (int kh = 0; kh < 2; ++kh)
      qf[rb][kh] = *(const bf16x8*)&Q[(base_bt + q0 + rb * 16 + llo) * DOUT +
                                      headoff + kh * 32 + lhi * 8];

  float m_r[2] = {-1e30f, -1e30f}, l_r[2] = {0.0f, 0.0f};
  f32x4 oa[2][4];
#pragma unroll
  for (int rb = 0; rb < 2; ++rb)
#pragma unroll
    for (int d = 0; d < 4; ++d)
#pragma unroll
      for (int r = 0; r < 4; ++r) oa[rb][d][r] = 0.0f;

  // staging slots: thread -> LDS slot (m = tid>>3, chunk c = tid&7)
  const int sm = tid >> 3, sc = tid & 7;
  // K row permutation: LDS row m holds global kv row pi(m)
  const int jg = sm >> 4, si = sm & 15;
  const int pi = (jg >> 1) * 32 + (si >> 2) * 8 + (jg & 1) * 4 + (si & 3);
  const int scs = (sc ^ (sm & 7)) * 8;  // inverse-swizzled source chunk

  const short* kgp = K + (base_bt + pi) * DOUT + headoff + scs;
  const short* vgp = Vt_g + (size_t)(headoff + sm) * BT + base_bt + scs;

  // per-lane kv bases of s[j][r]:  kv = (j>>1)*32 + lhi*8 + (j&1)*4 + r
  const int klb0 = lhi * 8, klb1 = lhi * 8 + 4;

  const int ktmax = qt * 4 + 3;

  // prologue: stage tile 0 into buf 0
  gload16(kgp, &Ks[0][wid * 8][0]);
  gload16(vgp, &Vt[0][wid * 8][0]);
  kgp += 64 * DOUT;
  vgp += 64;
  __syncthreads();

  for (int kt = 0; kt <= ktmax; ++kt) {
    const int cur = kt & 1, nxt = cur ^ 1;

    if (kt < ktmax) {  // issue next-tile async loads (drain at the barrier)
      gload16(kgp, &Ks[nxt][wid * 8][0]);
      gload16(vgp, &Vt[nxt][wid * 8][0]);
      kgp += 64 * DOUT;
      vgp += 64;
    }

    if (kt * 64 <= q0 + 31) {
      bf16x8 pb[2][2];
#pragma unroll
      for (int rb = 0; rb < 2; ++rb) {
        // S^T: s[j][r] = S[kv = (j>>1)*32+lhi*8+(j&1)*4+r][q = llo]
        f32x4 s[4];
        __builtin_amdgcn_s_setprio(1);
#pragma unroll
        for (int j = 0; j < 4; ++j) {
          const int row = j * 16 + llo;
          bf16x8 kfa = *(const bf16x8*)&Ks[cur][row][(lhi ^ lm7) * 8];
          bf16x8 kfb = *(const bf16x8*)&Ks[cur][row][((4 + lhi) ^ lm7) * 8];
#pragma unroll
          for (int r = 0; r < 4; ++r) s[j][r] = 0.0f;
          s[j] = MFMA16(kfa, qf[rb][0], s[j]);
          s[j] = MFMA16(kfb, qf[rb][1], s[j]);
        }
        __builtin_amdgcn_s_setprio(0);

        // causal mask (diagonal-overlap tiles only)
        if (kt * 64 + 63 > q0 + rb * 16) {
          const int qrel = q0 + rb * 16 + llo - kt * 64;
#pragma unroll
          for (int j = 0; j < 4; ++j) {
            const int kb = (j >> 1) * 32 + ((j & 1) ? klb1 : klb0);
#pragma unroll
            for (int r = 0; r < 4; ++r)
              if (kb + r > qrel) s[j][r] = -1e30f;
          }
        }

        // row max: in-lane tree + 2 cross-group shuffles (q = llo)
        float a0 = fmaxf(fmaxf(s[0][0], s[0][1]), fmaxf(s[0][2], s[0][3]));
        float a1 = fmaxf(fmaxf(s[1][0], s[1][1]), fmaxf(s[1][2], s[1][3]));
        float a2 = fmaxf(fmaxf(s[2][0], s[2][1]), fmaxf(s[2][2], s[2][3]));
        float a3 = fmaxf(fmaxf(s[3][0], s[3][1]), fmaxf(s[3][2], s[3][3]));
        float mx = fmaxf(fmaxf(a0, a1), fmaxf(a2, a3));
        mx = fmaxf(mx, __shfl_xor(mx, 16));
        mx = fmaxf(mx, __shfl_xor(mx, 32));

        // defer-max rescale (all per-lane now: q = llo)
        if (!__all(mx - m_r[rb] <= 8.0f)) {
          const float mnew = fmaxf(m_r[rb], mx);
          const float al = exp2f(m_r[rb] - mnew);
          m_r[rb] = mnew;
          l_r[rb] *= al;
#pragma unroll
          for (int d = 0; d < 4; ++d)
#pragma unroll
            for (int r = 0; r < 4; ++r) oa[rb][d][r] *= al;
        }
        const float mc = m_r[rb];
#pragma unroll
        for (int j = 0; j < 4; ++j)
#pragma unroll
          for (int r = 0; r < 4; ++r) s[j][r] = exp2f(s[j][r] - mc);
        float b0 = (s[0][0] + s[0][1]) + (s[0][2] + s[0][3]);
        float b1 = (s[1][0] + s[1][1]) + (s[1][2] + s[1][3]);
        float b2 = (s[2][0] + s[2][1]) + (s[2][2] + s[2][3]);
        float b3 = (s[3][0] + s[3][1]) + (s[3][2] + s[3][3]);
        float rs = (b0 + b1) + (b2 + b3);
        rs += __shfl_xor(rs, 16);
        rs += __shfl_xor(rs, 32);
        l_r[rb] += rs;

        // pack P in-lane: pb[rb][jj] covers k = lhi*8 + 0..7 (kv jj*32+8lhi..)
#pragma unroll
        for (int jj = 0; jj < 2; ++jj) {
          union { bf16x8 v; unsigned u[4]; } w;
          w.u[0] = pkbf(s[2 * jj][0], s[2 * jj][1]);
          w.u[1] = pkbf(s[2 * jj][2], s[2 * jj][3]);
          w.u[2] = pkbf(s[2 * jj + 1][0], s[2 * jj + 1][1]);
          w.u[3] = pkbf(s[2 * jj + 1][2], s[2 * jj + 1][3]);
          pb[rb][jj] = w.v;
        }
      }

      // O^T += V^T @ P^T : A = V^T[d][kv] from LDS, B = pb (in-lane)
#pragma unroll
      for (int d = 0; d < 4; ++d) {
        __builtin_amdgcn_s_setprio(1);
#pragma unroll
        for (int jj = 0; jj < 2; ++jj) {
          bf16x8 vfr = *(const bf16x8*)
              &Vt[cur][d * 16 + llo][((jj * 4 + lhi) ^ lm7) * 8];
          oa[0][d] = MFMA16(vfr, pb[0][jj], oa[0][d]);
          oa[1][d] = MFMA16(vfr, pb[1][jj], oa[1][d]);
        }
        __builtin_amdgcn_s_setprio(0);
      }
    }

    __syncthreads();
  }

  // finalize: oa[rb][d][r] = O^T[d = d*16+lhi*4+r][q = llo]; scale by 1/l
#pragma unroll
  for (int rb = 0; rb < 2; ++rb) {
    const float li = 1.0f / l_r[rb];
    const size_t rowoff = (base_bt + q0 + rb * 16 + llo) * DOUT + headoff;
#pragma unroll
    for (int d = 0; d < 4; ++d) {
      uint2 w;
      w.x = pkbf(oa[rb][d][0] * li, oa[rb][d][1] * li);
      w.y = pkbf(oa[rb][d][2] * li, oa[rb][d][3] * li);
      *(uint2*)&Ctx[rowoff + d * 16 + lhi * 4] = w;
    }
  }
}

// ---------------------------------------------------------------------------
extern "C" void kernel_launch(void* const* d_in, const int* in_sizes, int n_in,
                              void* d_out, int out_size, void* d_ws, size_t ws_size,
                              hipStream_t stream) {
  const float* x  = (const float*)d_in[0];
  const float* Wq = (const float*)d_in[1];
  const float* Wk = (const float*)d_in[2];
  const float* Wv = (const float*)d_in[3];
  const float* Wo = (const float*)d_in[4];
  const float* bo = (const float*)d_in[5];
  float* out = (float*)d_out;

  const size_t NTD = (size_t)Bb * Tt * DOUT;
  const size_t WSZ = (size_t)DIN * DOUT;
  short* xb  = (short*)d_ws;
  short* Wqt = xb + NTD;
  short* Wkt = Wqt + WSZ;   // Wqt/Wkt contiguous (QK z-indexing)
  short* Wvt = Wkt + WSZ;
  short* Wot = Wvt + WSZ;
  short* Qb  = Wot + WSZ;   // Qb/Kb contiguous (QK z-indexing)
  short* Kb  = Qb + NTD;
  short* Vtb = Kb + NTD;    // V^T [DOUT][BT]
  short* Cb  = Vtb + NTD;

  const int M = Bb * Tt;  // 8192
  const float qscale = 0.125f * 1.44269504089f;  // 1/sqrt(HD) * log2(e)

  cvt_x<<<dim3(NTD / 1024), 256, 0, stream>>>(x, xb);
  cvt_wt<<<dim3(16, 16, 4), 256, 0, stream>>>(Wq, Wk, Wv, Wo, Wqt, Wkt, Wvt, Wot);

  // Q (pre-scaled) and K projections
  gemm_bf16<true, false, false><<<dim3(64, 8, 2), 256, 0, stream>>>(
      xb, Wqt, nullptr, Qb, M, DOUT, DIN, qscale);
  // V^T projection: C[d][tok] = sum_k Wvt[d][k] * xb[tok][k]
  gemm_bf16<false, false, false><<<dim3(8, 64), 256, 0, stream>>>(
      Wvt, xb, nullptr, Vtb, DOUT, M, DIN, 1.0f);

  attn_bf16<<<dim3(512), 512, 0, stream>>>(Qb, Kb, Vtb, Cb);

  gemm_bf16<false, true, true><<<dim3(64, 8), 256, 0, stream>>>(
      Cb, Wot, bo, out, M, DOUT, DOUT, 1.0f);
}